// Round 4
// baseline (1238.844 us; speedup 1.0000x reference)
//
#include <hip/hip_runtime.h>
#include <math.h>
#include <stdint.h>

#define Bb 64
#define Nn 4096
#define Uu 64
#define RL 4224                         // 64*66
#define NU (Nn*Uu)
#define MATSZ ((size_t)Nn*(size_t)RL)   // elements per feature matrix
#define ELLW 112                        // ELL row capacity (avg nnz ~42, +10 sigma safe)
#define XSTR 360                        // K-stride (bf16) in gemm LDS, pad of 352

typedef __attribute__((ext_vector_type(8))) short short8;
typedef __attribute__((ext_vector_type(4))) float f32x4;
typedef __attribute__((ext_vector_type(2))) float f32x2;
typedef unsigned int uint;
typedef unsigned short ushort;

__device__ inline uint f2bf(float f){ uint u=__float_as_uint(f); u += 0x7fffu + ((u>>16)&1u); return u>>16; }
__device__ inline uint pack2(float a,float b){
  uint ua=__float_as_uint(a); ua+=0x7fffu+((ua>>16)&1u);
  uint ub=__float_as_uint(b); ub+=0x7fffu+((ub>>16)&1u);
  return (ua>>16)|(ub&0xffff0000u);
}
__device__ inline float blo(uint u){ return __uint_as_float(u << 16); }
__device__ inline float bhi(uint u){ return __uint_as_float(u & 0xffff0000u); }

// ---------------- ELL extraction: one pass, no scan ----------------
// pkv[row*112 + i] = (bf16(val)<<16) | col ; rcnt[row] = count rounded up to 4 (zero-padded)
__global__ __launch_bounds__(256) void k_fill(const float* __restrict__ sup,
                                              uint* __restrict__ pkv, int* __restrict__ rcnt) {
  const int lane = threadIdx.x & 63;
  const int row = blockIdx.x * 4 + (threadIdx.x >> 6);
  const float* rp = sup + (size_t)row * Nn;
  uint* outp = pkv + (size_t)row * ELLW;
  const unsigned long long lt = (1ull << lane) - 1ull;
  int off = 0;
  for (int j0 = 0; j0 < Nn; j0 += 64) {
    float v = rp[j0 + lane];
    unsigned long long m = __ballot(v != 0.0f);
    if (v != 0.0f) {
      int pos = off + (int)__popcll(m & lt);
      if (pos < ELLW) outp[pos] = (f2bf(v) << 16) | (uint)(j0 + lane);
    }
    off += (int)__popcll(m);
  }
  if (off > ELLW) off = ELLW;
  const int c4 = (off + 3) & ~3;                 // <= 112 since 112%4==0
  if (lane < c4 - off) outp[off + lane] = 0u;    // zero pad: contributes nothing
  if (lane == 0) rcnt[row] = c4;
}

// ---------------- x0 = [inputs | hx] bf16 in [n][b][f], vectorized ----------------
__global__ __launch_bounds__(256) void k_bx0(const float* __restrict__ inp, const float* __restrict__ hx,
                                             ushort* __restrict__ x0) {
  const int n = blockIdx.x;
  const int b = threadIdx.x >> 2, q = threadIdx.x & 3;     // 4 lanes per batch row, 16 u each
  const float* hp = hx + (size_t)b*NU + (size_t)n*Uu + q*16;
  ushort* xp = x0 + (size_t)n*RL + b*66;
  #pragma unroll
  for (int i = 0; i < 4; ++i) {
    const float4 v = *(const float4*)&hp[i*4];
    const int o = 2 + q*16 + i*4;
    *(uint*)&xp[o]     = pack2(v.x, v.y);       // 4B-aligned stores (o even)
    *(uint*)&xp[o + 2] = pack2(v.z, v.w);
  }
  if (q == 0) {
    const float2 iv = *(const float2*)&inp[(size_t)b*(size_t)(Nn*2) + (size_t)n*2];
    *(uint*)&xp[0] = pack2(iv.x, iv.y);
  }
}

// ---------------- 4-nnz batch: 4 ds_read_b64 + packed FMAs ----------------
__device__ __forceinline__ void nnz4(const uint4 e, const ushort* __restrict__ slab, const int cgo,
                                     f32x2& a01, f32x2& a23) {
  const uint2 w0 = *(const uint2*)&slab[(e.x & 0xffffu)*20u + cgo];
  const uint2 w1 = *(const uint2*)&slab[(e.y & 0xffffu)*20u + cgo];
  const uint2 w2 = *(const uint2*)&slab[(e.z & 0xffffu)*20u + cgo];
  const uint2 w3 = *(const uint2*)&slab[(e.w & 0xffffu)*20u + cgo];
  const float b0 = bhi(e.x), b1 = bhi(e.y), b2 = bhi(e.z), b3 = bhi(e.w);
  a01 += (f32x2){b0,b0} * (f32x2){blo(w0.x), bhi(w0.x)};
  a23 += (f32x2){b0,b0} * (f32x2){blo(w0.y), bhi(w0.y)};
  a01 += (f32x2){b1,b1} * (f32x2){blo(w1.x), bhi(w1.x)};
  a23 += (f32x2){b1,b1} * (f32x2){blo(w1.y), bhi(w1.y)};
  a01 += (f32x2){b2,b2} * (f32x2){blo(w2.x), bhi(w2.x)};
  a23 += (f32x2){b2,b2} * (f32x2){blo(w2.y), bhi(w2.y)};
  a01 += (f32x2){b3,b3} * (f32x2){blo(w3.x), bhi(w3.x)};
  a23 += (f32x2){b3,b3} * (f32x2){blo(w3.y), bhi(w3.y)};
}

// ---------------- SpMM: y = A@x (PASS2: y = 2*A@x - xsub), bf16 LDS slab ----------------
// 16-col bf16 slab, row stride 20 ushorts (40B, 160 KiB). XCD-contiguous unit schedule.
// Dual-row walk: each thread interleaves two rows' CSR streams -> 8 ds_reads in flight.
template<bool PASS2>
__global__ __launch_bounds__(1024) void k_spmm(const ushort* __restrict__ xin, const ushort* __restrict__ xsub,
                                               ushort* __restrict__ yout, const int* __restrict__ rcnt,
                                               const uint* __restrict__ pkv) {
  extern __shared__ ushort slab[];             // [4096][20], cols 0..15 used
  const int t = threadIdx.x, cg = t & 3, rs = t >> 2;   // 4 lanes per row
  const int cgo = cg * 4;                               // ushort offset of this lane's 4 cols
  const int xc = blockIdx.x & 7, sl = blockIdx.x >> 3;  // XCD, slot 0..31
  for (int uu = 0; uu < 3; ++uu) {
    int unit, r0, full;
    if (uu < 2) { unit = 66*xc + uu*32 + sl; r0 = 0;               full = 1; }
    else        { unit = 66*xc + 64 + (sl >> 4); r0 = (sl & 15)*256; full = 0; }
    const int s = unit / 264, sc = unit % 264, c0 = sc * 16;
    const ushort* xs = xin + (PASS2 ? (size_t)s*MATSZ : (size_t)0) + c0;
    if (uu) __syncthreads();
    for (int it = 0; it < 16; ++it) {          // stage all 4096 rows
      const int j = it*256 + rs;
      *(uint2*)&slab[j*20 + cgo] = *(const uint2*)&xs[(size_t)j*RL + cgo];
    }
    __syncthreads();
    const int rb = s * Nn;
    ushort* yo = yout + (size_t)s*MATSZ + c0;
    if (full) {
      for (int it = 0; it < 8; ++it) {
        const int rowA = it*512 + rs, rowB = rowA + 256;
        int pa = (rb + rowA)*ELLW, pb = (rb + rowB)*ELLW;
        const int pae = pa + rcnt[rb + rowA], pbe = pb + rcnt[rb + rowB];
        f32x2 A01 = {0.f,0.f}, A23 = {0.f,0.f}, B01 = {0.f,0.f}, B23 = {0.f,0.f};
        while (pa < pae && pb < pbe) {
          const uint4 ea = *(const uint4*)&pkv[pa]; pa += 4;
          const uint4 eb = *(const uint4*)&pkv[pb]; pb += 4;
          nnz4(ea, slab, cgo, A01, A23);
          nnz4(eb, slab, cgo, B01, B23);
        }
        for (; pa < pae; pa += 4) { const uint4 e = *(const uint4*)&pkv[pa]; nnz4(e, slab, cgo, A01, A23); }
        for (; pb < pbe; pb += 4) { const uint4 e = *(const uint4*)&pkv[pb]; nnz4(e, slab, cgo, B01, B23); }
        uint2 oA, oB;
        if (PASS2) {
          const uint2 xa = *(const uint2*)&xsub[(size_t)rowA*RL + c0 + cgo];
          const uint2 xb = *(const uint2*)&xsub[(size_t)rowB*RL + c0 + cgo];
          oA.x = pack2(2.f*A01.x - blo(xa.x), 2.f*A01.y - bhi(xa.x));
          oA.y = pack2(2.f*A23.x - blo(xa.y), 2.f*A23.y - bhi(xa.y));
          oB.x = pack2(2.f*B01.x - blo(xb.x), 2.f*B01.y - bhi(xb.x));
          oB.y = pack2(2.f*B23.x - blo(xb.y), 2.f*B23.y - bhi(xb.y));
        } else {
          oA.x = pack2(A01.x, A01.y); oA.y = pack2(A23.x, A23.y);
          oB.x = pack2(B01.x, B01.y); oB.y = pack2(B23.x, B23.y);
        }
        *(uint2*)&yo[(size_t)rowA*RL + cgo] = oA;
        *(uint2*)&yo[(size_t)rowB*RL + cgo] = oB;
      }
    } else {
      const int row = r0 + rs;
      int p = (rb + row)*ELLW;
      const int p1 = p + rcnt[rb + row];
      f32x2 a01 = {0.f,0.f}, a23 = {0.f,0.f};
      for (; p < p1; p += 4) { const uint4 e = *(const uint4*)&pkv[p]; nnz4(e, slab, cgo, a01, a23); }
      uint2 o;
      if (PASS2) {
        const uint2 xv = *(const uint2*)&xsub[(size_t)row*RL + c0 + cgo];
        o.x = pack2(2.f*a01.x - blo(xv.x), 2.f*a01.y - bhi(xv.x));
        o.y = pack2(2.f*a23.x - blo(xv.y), 2.f*a23.y - bhi(xv.y));
      } else {
        o.x = pack2(a01.x, a01.y); o.y = pack2(a23.x, a23.y);
      }
      *(uint2*)&yo[(size_t)row*RL + cgo] = o;
    }
  }
}

// ---------------- W pre-pack into MFMA B-fragment order (bf16) ----------------
__global__ __launch_bounds__(256) void k_wpack(const float* __restrict__ W1, const float* __restrict__ W2,
                                               ushort* __restrict__ Wp1, ushort* __restrict__ Wp2) {
  const int tid = blockIdx.x*256 + threadIdx.x;
  const int i = tid & 7, l = (tid >> 3) & 63;
  if (tid < 45056) {
    const int g = tid >> 9, tt = g / 11, kk = g % 11;
    const int r = kk*32 + (l>>4)*8 + i, c = tt*16 + (l & 15);
    Wp1[tid] = (r < 330) ? (ushort)f2bf(W1[(size_t)r*128 + c]) : (ushort)0;
  } else {
    const int t2 = tid - 45056;
    const int g = t2 >> 9, tt = g / 11, kk = g % 11;
    const int r = kk*32 + (l>>4)*8 + i, c = tt*16 + (l & 15);
    Wp2[t2] = (r < 330) ? (ushort)f2bf(W2[(size_t)r*64 + c]) : (ushort)0;
  }
}

// ---------------- gconv1 output GEMM (MFMA), fused sigmoid + r*hx + u ----------------
__global__ __launch_bounds__(256) void k_gemm1(const ushort* __restrict__ x0, const ushort* __restrict__ y1,
                                               const ushort* __restrict__ y2, const ushort* __restrict__ Wp,
                                               const float* __restrict__ bias, const float* __restrict__ hx,
                                               ushort* __restrict__ x0w, ushort* __restrict__ ubuf) {
  __shared__ ushort Xs[64*XSTR];                  // [b][k], k = f*5+m, padded to 352
  const int n = blockIdx.x, t = threadIdx.x;
  for (int q = t; q < 64*XSTR/4; q += 256) ((unsigned long long*)Xs)[q] = 0ull;
  __syncthreads();
  for (int m = 0; m < 5; ++m) {
    const ushort* mp;
    if (m == 0) mp = x0; else { mp = (m & 1) ? y1 : y2; if (m >= 3) mp += MATSZ; }
    mp += (size_t)n * RL;
    for (int q = t; q < RL; q += 256) {
      const int b = q / 66, f = q - b*66;
      Xs[b*XSTR + f*5 + m] = mp[q];
    }
  }
  __syncthreads();
  const int w = t >> 6, l = t & 63;
  const int b0 = w * 16;
  f32x4 acc[8];
  for (int i = 0; i < 8; ++i) acc[i] = (f32x4){0.f,0.f,0.f,0.f};
  const int arow = b0 + (l & 15), koff0 = (l >> 4) * 8;
  for (int kk = 0; kk < 11; ++kk) {
    const short8 af = *(const short8*)&Xs[arow*XSTR + kk*32 + koff0];
    #pragma unroll
    for (int tt = 0; tt < 8; ++tt) {
      const short8 bf = *(const short8*)&Wp[(((size_t)tt*11 + kk)*64 + l)*8];
      acc[tt] = __builtin_amdgcn_mfma_f32_16x16x32_bf16(af, bf, acc[tt], 0, 0, 0);
    }
  }
  const int rg = (l >> 4) * 4;
  #pragma unroll
  for (int tt = 0; tt < 8; ++tt) {
    const int o = tt*16 + (l & 15);
    const float bs = bias[o];
    #pragma unroll
    for (int r = 0; r < 4; ++r) {
      const int b = b0 + rg + r;
      const float v = acc[tt][r] + bs;
      const float sg = 1.0f / (1.0f + __expf(-v));
      if (o < Uu) {
        const float h = hx[(size_t)b*NU + (size_t)n*Uu + o];
        x0w[(size_t)n*RL + b*66 + 2 + o] = (ushort)f2bf(sg * h);
      } else {
        ubuf[(size_t)b*NU + (size_t)n*Uu + (o - Uu)] = (ushort)f2bf(sg);
      }
    }
  }
}

// ---------------- gconv2 output GEMM (MFMA), fused tanh + final gate ----------------
__global__ __launch_bounds__(256) void k_gemm2(const ushort* __restrict__ x0, const ushort* __restrict__ y1,
                                               const ushort* __restrict__ y2, const ushort* __restrict__ Wp,
                                               const float* __restrict__ bias, const float* __restrict__ hx,
                                               const ushort* __restrict__ ubuf, float* __restrict__ out) {
  __shared__ ushort Xs[64*XSTR];
  const int n = blockIdx.x, t = threadIdx.x;
  for (int q = t; q < 64*XSTR/4; q += 256) ((unsigned long long*)Xs)[q] = 0ull;
  __syncthreads();
  for (int m = 0; m < 5; ++m) {
    const ushort* mp;
    if (m == 0) mp = x0; else { mp = (m & 1) ? y1 : y2; if (m >= 3) mp += MATSZ; }
    mp += (size_t)n * RL;
    for (int q = t; q < RL; q += 256) {
      const int b = q / 66, f = q - b*66;
      Xs[b*XSTR + f*5 + m] = mp[q];
    }
  }
  __syncthreads();
  const int w = t >> 6, l = t & 63;
  const int b0 = w * 16;
  f32x4 acc[4];
  for (int i = 0; i < 4; ++i) acc[i] = (f32x4){0.f,0.f,0.f,0.f};
  const int arow = b0 + (l & 15), koff0 = (l >> 4) * 8;
  for (int kk = 0; kk < 11; ++kk) {
    const short8 af = *(const short8*)&Xs[arow*XSTR + kk*32 + koff0];
    #pragma unroll
    for (int tt = 0; tt < 4; ++tt) {
      const short8 bf = *(const short8*)&Wp[(((size_t)tt*11 + kk)*64 + l)*8];
      acc[tt] = __builtin_amdgcn_mfma_f32_16x16x32_bf16(af, bf, acc[tt], 0, 0, 0);
    }
  }
  const int rg = (l >> 4) * 4;
  #pragma unroll
  for (int tt = 0; tt < 4; ++tt) {
    const int o = tt*16 + (l & 15);
    const float bs = bias[o];
    #pragma unroll
    for (int r = 0; r < 4; ++r) {
      const int b = b0 + rg + r;
      const float c = tanhf(acc[tt][r] + bs);
      const size_t ix = (size_t)b*NU + (size_t)n*Uu + o;
      const float u = __uint_as_float(((uint)ubuf[ix]) << 16);
      const float h = hx[ix];
      out[ix] = u*h + (1.0f - u)*c;
    }
  }
}

extern "C" void kernel_launch(void* const* d_in, const int* in_sizes, int n_in,
                              void* d_out, int out_size, void* d_ws, size_t ws_size,
                              hipStream_t stream) {
  const float* inp = (const float*)d_in[0];
  const float* hx  = (const float*)d_in[1];
  const float* sup = (const float*)d_in[2];
  const float* ruW = (const float*)d_in[3];
  const float* ruB = (const float*)d_in[4];
  const float* gW  = (const float*)d_in[5];
  const float* gB  = (const float*)d_in[6];
  float* out = (float*)d_out;

  // workspace (bf16 intermediates): x0 | y1[2] | y2[2] | u | Wpk | ELL
  ushort* x0   = (ushort*)d_ws;
  ushort* y1   = x0 + MATSZ;
  ushort* y2   = y1 + 2*MATSZ;
  ushort* ubuf = y2 + 2*MATSZ;
  ushort* Wp1  = ubuf + (size_t)Bb*NU;
  ushort* Wp2  = Wp1 + 45056;
  uint* pkv  = (uint*)(Wp2 + 22528);          // 8192*112 uints, 16B-aligned streams
  int*  rcnt = (int*)(pkv + 8192*ELLW);

  hipFuncSetAttribute(reinterpret_cast<const void*>(&k_spmm<false>),
                      hipFuncAttributeMaxDynamicSharedMemorySize, 163840);
  hipFuncSetAttribute(reinterpret_cast<const void*>(&k_spmm<true>),
                      hipFuncAttributeMaxDynamicSharedMemorySize, 163840);

  k_fill<<<2048, 256, 0, stream>>>(sup, pkv, rcnt);
  k_wpack<<<264, 256, 0, stream>>>(ruW, gW, Wp1, Wp2);
  k_bx0<<<Nn, 256, 0, stream>>>(inp, hx, x0);

  // gconv1
  k_spmm<false><<<256, 1024, 163840, stream>>>(x0, nullptr, y1, rcnt, pkv);
  k_spmm<true ><<<256, 1024, 163840, stream>>>(y1, x0,      y2, rcnt, pkv);
  k_gemm1<<<Nn, 256, 0, stream>>>(x0, y1, y2, Wp1, ruB, hx, x0, ubuf);
  // gconv2 (x0 state slots now hold bf16(r*hx))
  k_spmm<false><<<256, 1024, 163840, stream>>>(x0, nullptr, y1, rcnt, pkv);
  k_spmm<true ><<<256, 1024, 163840, stream>>>(y1, x0,      y2, rcnt, pkv);
  k_gemm2<<<Nn, 256, 0, stream>>>(x0, y1, y2, Wp2, gB, hx, ubuf, out);
}